// Round 5
// baseline (3536.217 us; speedup 1.0000x reference)
//
#include <hip/hip_runtime.h>
#include <math.h>

#define N_NODES  25000
#define N_EDGES  300000
#define N_GRAPHS 256
#define EMB_DIM  92
#define HID      256

typedef short bf16x8 __attribute__((ext_vector_type(8)));
typedef float f32x4  __attribute__((ext_vector_type(4)));

// fast softplus == jax.nn.softplus to ~1e-6 abs
__device__ __forceinline__ float softplusf(float x){
    return fmaxf(x, 0.0f) + __logf(1.0f + __expf(-fabsf(x)));
}
__device__ __forceinline__ unsigned short f2bf(float f){
    unsigned int u = __float_as_uint(f);
    unsigned int r = (u + 0x7FFFu + ((u >> 16) & 1u)) >> 16;
    return (unsigned short)r;
}
__device__ __forceinline__ float bf2f(unsigned short b){
    return __uint_as_float(((unsigned int)b) << 16);
}
// truncation hi/lo split; error <= 2^-16|h|, absorbed by 3-term MFMA scheme
__device__ __forceinline__ void split_bf(float h, unsigned short& hi, unsigned short& lo){
    const unsigned int u = __float_as_uint(h);
    hi = (unsigned short)(u >> 16);
    const float r = h - __uint_as_float(u & 0xFFFF0000u);
    lo = (unsigned short)(__float_as_uint(r) >> 16);
}

// ---------------------------------------------------------------- embedding gather -> x92 [N,92]
__global__ void gather_emb_kernel(const int* __restrict__ atoms,
                                  const float* __restrict__ emb,
                                  float* __restrict__ x)
{
    const int n = blockIdx.x;
    const int c = threadIdx.x;
    if (c < EMB_DIM){
        const int a = atoms[n];
        x[(size_t)n*EMB_DIM + c] = emb[(size_t)a*EMB_DIM + c];
    }
}

// ---------------------------------------------------------------- counting sort by dst (CSR build)
__global__ __launch_bounds__(256) void hist_kernel(const int* __restrict__ dst, int* __restrict__ hist){
    const int e = blockIdx.x*256 + threadIdx.x;
    if (e < N_EDGES) atomicAdd(&hist[dst[e]], 1);
}

__global__ __launch_bounds__(1024) void scan_kernel(const int* __restrict__ hist,
                                                    int* __restrict__ row_ptr,
                                                    int* __restrict__ cursor){
    __shared__ int chunk[1024];
    const int t = threadIdx.x;
    const int base = t*25;                     // 1024*25 = 25600 >= 25000
    int local[25];
    int s = 0;
    #pragma unroll
    for (int i=0;i<25;i++){
        const int idx = base+i;
        const int v = (idx < N_NODES) ? hist[idx] : 0;
        local[i] = s; s += v;
    }
    chunk[t] = s;
    __syncthreads();
    for (int off=1; off<1024; off<<=1){
        int v = (t >= off) ? chunk[t-off] : 0;
        __syncthreads();
        chunk[t] += v;
        __syncthreads();
    }
    const int pre = (t > 0) ? chunk[t-1] : 0;
    #pragma unroll
    for (int i=0;i<25;i++){
        const int idx = base+i;
        if (idx < N_NODES){
            const int v = pre + local[i];
            row_ptr[idx] = v;
            cursor[idx]  = v;
        }
    }
    if (t == 0) row_ptr[N_NODES] = N_EDGES;
}

__global__ __launch_bounds__(256) void scatter_kernel(const int* __restrict__ src, const int* __restrict__ dst,
                                                      int* __restrict__ cursor,
                                                      int* __restrict__ perm_s, int* __restrict__ src_s,
                                                      int* __restrict__ dst_s){
    const int e = blockIdx.x*256 + threadIdx.x;
    if (e < N_EDGES){
        const int d = dst[e];
        const int pos = atomicAdd(&cursor[d], 1);
        perm_s[pos] = e;
        src_s[pos]  = src[e];
        dst_s[pos]  = d;
    }
}

// ---------------------------------------------------------------- pack [3][256][256] fp32 weights into MFMA B-frag hi/lo bf16
__global__ __launch_bounds__(256) void pack_w_kernel(const float* __restrict__ w,
                                                     unsigned short* __restrict__ whi,
                                                     unsigned short* __restrict__ wlo)
{
    const int f     = blockIdx.x;          // 0..383
    const int layer = f >> 7;
    const int rem   = f & 127;
    const int ntile = rem >> 3;
    const int k8    = rem & 7;
    for (int i = threadIdx.x; i < 512; i += 256){
        const int lane = i >> 3, j = i & 7;
        const int k = k8*32 + (lane >> 4)*8 + j;
        const int n = ntile*16 + (lane & 15);
        const float v = w[(size_t)layer*HID*HID + (size_t)k*HID + n];
        const unsigned short hb = f2bf(v);
        whi[(size_t)f*512 + i] = hb;
        wlo[(size_t)f*512 + i] = f2bf(v - bf2f(hb));
    }
}

// ---------------------------------------------------------------- fused layer 0 (C=92, fp32): edge conv + aggregate + node linear
// block owns 16 nodes; edges [row_ptr[n0], row_ptr[n0+16]) processed in pairs of 16-edge tiles by two thread groups.
__global__ __launch_bounds__(256) void fused_layer92_kernel(
    const int* __restrict__ row_ptr,
    const int* __restrict__ perm_s, const int* __restrict__ src_s, const int* __restrict__ dst_s,
    const float* __restrict__ ea,
    const float* __restrict__ w1, const float* __restrict__ b1,     // [4][92],[92]
    const float* __restrict__ w2, const float* __restrict__ b2,     // [92][92],[92]
    const float* __restrict__ nw, const float* __restrict__ nb,     // [92][256],[256]
    const float* __restrict__ x92, float* __restrict__ xout)        // [N,92] -> [N,256]
{
    constexpr int C  = EMB_DIM;   // 92
    constexpr int LP = 96;
    __shared__ float h1[2][16][LP];
    __shared__ float accG[2][16][LP];

    const int n0 = blockIdx.x * 16;
    const int nEnd = (n0 + 16 < N_NODES) ? n0 + 16 : N_NODES;
    const int row_begin = row_ptr[n0];
    const int row_end   = row_ptr[nEnd];
    const int tid = threadIdx.x;

    for (int idx = tid; idx < 2*16*LP; idx += 256) ((float*)accG)[idx] = 0.0f;

    const int grp = tid >> 7;      // 0/1
    const int c   = tid & 127;

    for (int base = row_begin; base < row_end; base += 32){
        // phase 1: h1 for both tiles (2*16*92 values)
        for (int idx = tid; idx < 2944; idx += 256){
            const int tile = idx / 1472;
            const int rem  = idx - tile*1472;
            const int e = rem / 92;
            const int k = rem - e*92;
            const int eid = base + tile*16 + e;
            float h = 0.0f;
            if (eid < row_end){
                const float4 a = *(const float4*)(ea + (size_t)perm_s[eid]*4);
                h = softplusf(fmaf(a.x, w1[k], fmaf(a.y, w1[C+k],
                              fmaf(a.z, w1[2*C+k], fmaf(a.w, w1[3*C+k], b1[k])))));
            }
            h1[tile][e][k] = h;
        }
        __syncthreads();

        // phase 2: group grp processes its tile; col-exclusive LDS accumulate (no atomics)
        if (c < C){
            const int tstart = base + grp*16;
            int cnt = row_end - tstart;
            cnt = cnt < 0 ? 0 : (cnt > 16 ? 16 : cnt);
            int dprev = -1; float run = 0.0f;
            for (int e=0;e<cnt;e++){
                const int eid = tstart + e;
                const int s = src_s[eid], d = dst_s[eid];
                float acc = 0.0f;
                for (int k=0;k<C;k+=4){
                    const float4 hv = *(const float4*)&h1[grp][e][k];
                    acc = fmaf(hv.x, w2[(k+0)*C+c], fmaf(hv.y, w2[(k+1)*C+c],
                          fmaf(hv.z, w2[(k+2)*C+c], fmaf(hv.w, w2[(k+3)*C+c], acc))));
                }
                const float msg = (acc + b2[c]) * x92[(size_t)s*C + c];
                if (d != dprev){
                    if (dprev >= 0){ accG[grp][dprev-n0][c] += run; run = 0.0f; }
                    dprev = d;
                }
                run += msg;
            }
            if (dprev >= 0) accG[grp][dprev-n0][c] += run;
        }
        __syncthreads();
    }
    __syncthreads();

    // node linear fp32: xout = softplus((acc0+acc1) @ nw + nb)
    const int cc = tid;
    for (int i=0;i<16;i++){
        const int node = n0 + i;
        if (node >= N_NODES) break;
        float acc = nb[cc];
        for (int k=0;k<C;k++){
            const float av = accG[0][i][k] + accG[1][i][k];
            acc = fmaf(av, nw[(size_t)k*HID + cc], acc);
        }
        xout[(size_t)node*HID + cc] = softplusf(acc);
    }
}

// ---------------------------------------------------------------- fused layers 1-3 (C=256): edge MLP (MFMA) + LDS aggregate + node linear (MFMA)
// block owns 16 nodes; 32-edge MFMA tiles; LDS f32 accumulator; zero global atomics.
__global__ __launch_bounds__(256) void fused_layer256_kernel(
    const int* __restrict__ row_ptr,
    const int* __restrict__ perm_s, const int* __restrict__ src_s, const int* __restrict__ dst_s,
    const float* __restrict__ ea,
    const float* __restrict__ w1, const float* __restrict__ b1,
    const unsigned short* __restrict__ whi, const unsigned short* __restrict__ wlo,
    const float* __restrict__ b2,
    const unsigned short* __restrict__ nwhi, const unsigned short* __restrict__ nwlo,
    const float* __restrict__ nb,
    const float* __restrict__ xin, float* __restrict__ xout)
{
    constexpr int C   = HID;
    constexpr int LDA = C + 8;
    __shared__ unsigned short aHi[32][LDA];   // 16.9 KB
    __shared__ unsigned short aLo[32][LDA];   // 16.9 KB
    __shared__ float accS[16][LDA];           // 16.9 KB

    const int n0 = blockIdx.x * 16;
    const int nEnd = (n0 + 16 < N_NODES) ? n0 + 16 : N_NODES;
    const int row_begin = row_ptr[n0];
    const int row_end   = row_ptr[nEnd];
    const int tid  = threadIdx.x;
    const int lane = tid & 63, wv = tid >> 6;
    const int quad = lane >> 4, fcol = lane & 15;

    #pragma unroll
    for (int i=0;i<16;i++) accS[i][tid] = 0.0f;

    const float w10 = w1[tid], w11 = w1[C+tid], w12 = w1[2*C+tid], w13 = w1[3*C+tid];
    const float bk  = b1[tid];
    float bb[4];
    #pragma unroll
    for (int t=0;t<4;t++) bb[t] = b2[(wv*4+t)*16 + fcol];

    for (int tb = row_begin; tb < row_end; tb += 32){
        // phase 1: h1 = softplus(ea@w1+b1) -> hi/lo bf16 staging (thread = channel)
        {
            const int k = tid;
            for (int e=0;e<32;e++){
                const int eid = tb + e;
                float h = 0.0f;
                if (eid < row_end){
                    const float4 a = *(const float4*)(ea + (size_t)perm_s[eid]*4);
                    h = softplusf(fmaf(a.x,w10,fmaf(a.y,w11,fmaf(a.z,w12,fmaf(a.w,w13,bk)))));
                }
                unsigned short hb, lb; split_bf(h, hb, lb);
                aHi[e][k] = hb; aLo[e][k] = lb;
            }
        }
        __syncthreads();

        // phase 2: ee = h1 @ w2 (split-bf16, 3 MFMA)
        f32x4 acc[2][4];
        #pragma unroll
        for (int m=0;m<2;m++)
            #pragma unroll
            for (int t=0;t<4;t++)
                #pragma unroll
                for (int j=0;j<4;j++) acc[m][t][j] = 0.0f;

        for (int k8=0;k8<8;k8++){
            bf16x8 ah[2], al[2];
            #pragma unroll
            for (int m=0;m<2;m++){
                ah[m] = *(const bf16x8*)(&aHi[m*16 + fcol][0] + k8*32 + quad*8);
                al[m] = *(const bf16x8*)(&aLo[m*16 + fcol][0] + k8*32 + quad*8);
            }
            #pragma unroll
            for (int t=0;t<4;t++){
                const int fi = (wv*4 + t)*8 + k8;
                const bf16x8 bh = *(const bf16x8*)(whi + (size_t)fi*512 + lane*8);
                const bf16x8 bl = *(const bf16x8*)(wlo + (size_t)fi*512 + lane*8);
                #pragma unroll
                for (int m=0;m<2;m++){
                    acc[m][t] = __builtin_amdgcn_mfma_f32_16x16x32_bf16(ah[m], bh, acc[m][t], 0, 0, 0);
                    acc[m][t] = __builtin_amdgcn_mfma_f32_16x16x32_bf16(ah[m], bl, acc[m][t], 0, 0, 0);
                    acc[m][t] = __builtin_amdgcn_mfma_f32_16x16x32_bf16(al[m], bh, acc[m][t], 0, 0, 0);
                }
            }
        }

        // epilogue: msg = (ee+b2)*x[src]; run-merge; LDS atomic accumulate into block-local acc
        #pragma unroll
        for (int m=0;m<2;m++){
            const int ebase = tb + m*16 + quad*4;
            int dprev = -1;
            float run[4] = {0.f,0.f,0.f,0.f};
            #pragma unroll
            for (int i=0;i<4;i++){
                const int eid = ebase + i;
                if (eid >= row_end) break;
                const int s = src_s[eid], d = dst_s[eid];
                if (d != dprev){
                    if (dprev >= 0){
                        #pragma unroll
                        for (int t=0;t<4;t++){
                            atomicAdd(&accS[dprev - n0][(wv*4+t)*16 + fcol], run[t]);
                            run[t] = 0.0f;
                        }
                    }
                    dprev = d;
                }
                #pragma unroll
                for (int t=0;t<4;t++){
                    const int n = (wv*4+t)*16 + fcol;
                    run[t] += (acc[m][t][i] + bb[t]) * xin[(size_t)s*C + n];
                }
            }
            if (dprev >= 0){
                #pragma unroll
                for (int t=0;t<4;t++)
                    atomicAdd(&accS[dprev - n0][(wv*4+t)*16 + fcol], run[t]);
            }
        }
        __syncthreads();
    }
    __syncthreads();

    // node linear: accS[16][256] @ nw + nb -> softplus -> xout (plain stores)
    #pragma unroll
    for (int i=0;i<16;i++){
        unsigned short hb, lb; split_bf(accS[i][tid], hb, lb);
        aHi[i][tid] = hb; aLo[i][tid] = lb;
    }
    __syncthreads();

    f32x4 acc2[4];
    #pragma unroll
    for (int t=0;t<4;t++)
        #pragma unroll
        for (int j=0;j<4;j++) acc2[t][j] = 0.0f;

    const unsigned short* aHrow = &aHi[fcol][0];
    const unsigned short* aLrow = &aLo[fcol][0];
    for (int k8=0;k8<8;k8++){
        const bf16x8 ah = *(const bf16x8*)(aHrow + k8*32 + quad*8);
        const bf16x8 al = *(const bf16x8*)(aLrow + k8*32 + quad*8);
        #pragma unroll
        for (int t=0;t<4;t++){
            const int fi = (wv*4 + t)*8 + k8;
            const bf16x8 bh = *(const bf16x8*)(nwhi + (size_t)fi*512 + lane*8);
            const bf16x8 bl = *(const bf16x8*)(nwlo + (size_t)fi*512 + lane*8);
            acc2[t] = __builtin_amdgcn_mfma_f32_16x16x32_bf16(ah, bh, acc2[t], 0, 0, 0);
            acc2[t] = __builtin_amdgcn_mfma_f32_16x16x32_bf16(ah, bl, acc2[t], 0, 0, 0);
            acc2[t] = __builtin_amdgcn_mfma_f32_16x16x32_bf16(al, bh, acc2[t], 0, 0, 0);
        }
    }

    #pragma unroll
    for (int i=0;i<4;i++){
        const int node = n0 + quad*4 + i;
        if (node < N_NODES){
            #pragma unroll
            for (int t=0;t<4;t++){
                const int n = (wv*4+t)*16 + fcol;
                xout[(size_t)node*C + n] = softplusf(acc2[t][i] + nb[n]);
            }
        }
    }
}

// ---------------------------------------------------------------- mean pool, run-merged (batch is sorted)
__global__ __launch_bounds__(256) void pool_kernel(
    const float* __restrict__ x, const int* __restrict__ batch,
    float* __restrict__ sums, float* __restrict__ cnts)
{
    constexpr int NPB = 32;
    const int n0 = blockIdx.x * NPB;
    const int c  = threadIdx.x;
    int gprev = batch[n0];
    float run = 0.0f, crun = 0.0f;
    for (int i=0;i<NPB;i++){
        const int n = n0 + i;
        if (n >= N_NODES) break;
        const int g = batch[n];
        if (g != gprev){
            atomicAdd(&sums[(size_t)gprev*HID + c], run);
            if (c == 0) atomicAdd(&cnts[gprev], crun);
            run = 0.0f; crun = 0.0f; gprev = g;
        }
        run  += x[(size_t)n*HID + c];
        crun += 1.0f;
    }
    atomicAdd(&sums[(size_t)gprev*HID + c], run);
    if (c == 0) atomicAdd(&cnts[gprev], crun);
}

// ---------------------------------------------------------------- readout MLP (one block per graph)
__global__ __launch_bounds__(256) void readout_kernel(
    const float* __restrict__ sums, const float* __restrict__ cnts,
    const float* __restrict__ rw1, const float* __restrict__ rb1,
    const float* __restrict__ rw2, const float* __restrict__ rb2,
    const float* __restrict__ rw3, const float* __restrict__ rb3,
    float* __restrict__ out)
{
    __shared__ float g[HID];
    __shared__ float h[HID];
    __shared__ float h2[HID/2];
    __shared__ float red[256];
    const int gi = blockIdx.x;
    const int t  = threadIdx.x;
    const float cnt = fmaxf(cnts[gi], 1.0f);
    g[t] = sums[(size_t)gi*HID + t] / cnt;
    __syncthreads();
    float acc = rb1[t];
    for (int k=0;k<HID;k++) acc = fmaf(g[k], rw1[(size_t)k*HID + t], acc);
    h[t] = softplusf(acc);
    __syncthreads();
    if (t < HID/2){
        float a2 = rb2[t];
        for (int k=0;k<HID;k++) a2 = fmaf(h[k], rw2[(size_t)k*(HID/2) + t], a2);
        h2[t] = softplusf(a2);
    }
    __syncthreads();
    red[t] = (t < HID/2) ? h2[t]*rw3[t] : 0.0f;
    __syncthreads();
    for (int s2=128; s2>0; s2>>=1){
        if (t < s2) red[t] += red[t+s2];
        __syncthreads();
    }
    if (t == 0) out[gi] = red[0] + rb3[0];
}

// ---------------------------------------------------------------- launcher
extern "C" void kernel_launch(void* const* d_in, const int* in_sizes, int n_in,
                              void* d_out, int out_size, void* d_ws, size_t ws_size,
                              hipStream_t stream)
{
    const int*   x_atoms = (const int*)d_in[0];
    const int*   eidx    = (const int*)d_in[1];
    const int*   src     = eidx;               // edge_index[0]
    const int*   dst     = eidx + N_EDGES;     // edge_index[1]
    const float* ea      = (const float*)d_in[2];
    const int*   batch   = (const int*)d_in[3];
    const float* emb     = (const float*)d_in[4];
    const float* ew1_0   = (const float*)d_in[5];
    const float* eb1_0   = (const float*)d_in[6];
    const float* ew2_0   = (const float*)d_in[7];
    const float* eb2_0   = (const float*)d_in[8];
    const float* nw_0    = (const float*)d_in[9];
    const float* nb_0    = (const float*)d_in[10];
    const float* ew1     = (const float*)d_in[11];
    const float* eb1     = (const float*)d_in[12];
    const float* ew2     = (const float*)d_in[13];
    const float* eb2     = (const float*)d_in[14];
    const float* nw      = (const float*)d_in[15];
    const float* nb      = (const float*)d_in[16];
    const float* rw1     = (const float*)d_in[17];
    const float* rb1     = (const float*)d_in[18];
    const float* rw2     = (const float*)d_in[19];
    const float* rb2     = (const float*)d_in[20];
    const float* rw3     = (const float*)d_in[21];
    const float* rb3     = (const float*)d_in[22];
    float* out = (float*)d_out;

    // workspace: xA[N*256] | xB[N*256] (x92 aliases xB) | sums | cnts | 4x w-frag | hist | row_ptr | cursor | perm/src/dst
    float* xA   = (float*)d_ws;
    float* xB   = xA + (size_t)N_NODES*HID;
    float* x92  = xB;                                   // [N,92] lives in xB region before layer 1
    float* sums = xB + (size_t)N_NODES*HID;
    float* cnts = sums + (size_t)N_GRAPHS*HID;
    unsigned short* whi  = (unsigned short*)(cnts + N_GRAPHS);
    unsigned short* wlo  = whi  + (size_t)3*128*512;
    unsigned short* nwhi = wlo  + (size_t)3*128*512;
    unsigned short* nwlo = nwhi + (size_t)3*128*512;
    int* hist    = (int*)(nwlo + (size_t)3*128*512);
    int* row_ptr = hist + N_NODES;
    int* cursor  = row_ptr + (N_NODES + 1);
    int* perm_s  = cursor + N_NODES;
    int* src_s   = perm_s + N_EDGES;
    int* dst_s   = src_s  + N_EDGES;

    const int NBLK = (N_NODES + 15) / 16;   // 1563

    // ---- CSR build (counting sort by dst) ----
    hipMemsetAsync(hist, 0, N_NODES*sizeof(int), stream);
    hipLaunchKernelGGL(hist_kernel, dim3((N_EDGES+255)/256), dim3(256), 0, stream, dst, hist);
    hipLaunchKernelGGL(scan_kernel, dim3(1), dim3(1024), 0, stream, hist, row_ptr, cursor);
    hipLaunchKernelGGL(scatter_kernel, dim3((N_EDGES+255)/256), dim3(256), 0, stream,
                       src, dst, cursor, perm_s, src_s, dst_s);

    // ---- pack weights for MFMA ----
    hipLaunchKernelGGL(pack_w_kernel, dim3(384), dim3(256), 0, stream, ew2, whi, wlo);
    hipLaunchKernelGGL(pack_w_kernel, dim3(384), dim3(256), 0, stream, nw, nwhi, nwlo);

    // ---- layer 0 (fp32, fused) ----
    hipLaunchKernelGGL(gather_emb_kernel, dim3(N_NODES), dim3(128), 0, stream, x_atoms, emb, x92);
    hipLaunchKernelGGL(fused_layer92_kernel, dim3(NBLK), dim3(256), 0, stream,
                       row_ptr, perm_s, src_s, dst_s, ea,
                       ew1_0, eb1_0, ew2_0, eb2_0, nw_0, nb_0, x92, xA);

    // ---- layers 1..3 (MFMA, fused); ping-pong xA/xB ----
    const float* xi[3] = { xA, xB, xA };
    float*       xo[3] = { xB, xA, xB };
    for (int i=0;i<3;i++){
        hipLaunchKernelGGL(fused_layer256_kernel, dim3(NBLK), dim3(256), 0, stream,
                           row_ptr, perm_s, src_s, dst_s, ea,
                           ew1 + (size_t)i*4*HID, eb1 + (size_t)i*HID,
                           whi + (size_t)i*128*512, wlo + (size_t)i*128*512,
                           eb2 + (size_t)i*HID,
                           nwhi + (size_t)i*128*512, nwlo + (size_t)i*128*512,
                           nb + (size_t)i*HID,
                           xi[i], xo[i]);
    }

    // ---- pool + readout (final x is xB) ----
    hipMemsetAsync(sums, 0, ((size_t)N_GRAPHS*HID + N_GRAPHS)*sizeof(float), stream);
    hipLaunchKernelGGL(pool_kernel, dim3((N_NODES+31)/32), dim3(256), 0, stream, xB, batch, sums, cnts);
    hipLaunchKernelGGL(readout_kernel, dim3(N_GRAPHS), dim3(256), 0, stream,
                       sums, cnts, rw1, rb1, rw2, rb2, rw3, rb3, out);
}

// Round 6
// 1260.033 us; speedup vs baseline: 2.8064x; 2.8064x over previous
//
#include <hip/hip_runtime.h>
#include <math.h>

#define N_NODES  25000
#define N_EDGES  300000
#define N_GRAPHS 256
#define EMB_DIM  92
#define HID      256

typedef short bf16x8 __attribute__((ext_vector_type(8)));
typedef float f32x4  __attribute__((ext_vector_type(4)));

// fast softplus == jax.nn.softplus to ~1e-6 abs
__device__ __forceinline__ float softplusf(float x){
    return fmaxf(x, 0.0f) + __logf(1.0f + __expf(-fabsf(x)));
}
__device__ __forceinline__ unsigned short f2bf(float f){
    unsigned int u = __float_as_uint(f);
    unsigned int r = (u + 0x7FFFu + ((u >> 16) & 1u)) >> 16;   // RNE
    return (unsigned short)r;
}
__device__ __forceinline__ float bf2f(unsigned short b){
    return __uint_as_float(((unsigned int)b) << 16);
}
// truncation hi/lo split (used for node-update A operand; 3-MFMA scheme)
__device__ __forceinline__ void split_bf(float h, unsigned short& hi, unsigned short& lo){
    const unsigned int u = __float_as_uint(h);
    hi = (unsigned short)(u >> 16);
    const float r = h - __uint_as_float(u & 0xFFFF0000u);
    lo = (unsigned short)(__float_as_uint(r) >> 16);
}

// ---------------------------------------------------------------- embedding gather
__global__ void gather_emb_kernel(const int* __restrict__ atoms,
                                  const float* __restrict__ emb,
                                  float* __restrict__ x)
{
    const int n = blockIdx.x;
    const int c = threadIdx.x;
    if (c < EMB_DIM){
        const int a = atoms[n];
        x[(size_t)n*EMB_DIM + c] = emb[(size_t)a*EMB_DIM + c];
    }
}

// ---------------------------------------------------------------- counting sort by dst
__global__ __launch_bounds__(256) void hist_kernel(const int* __restrict__ dst, int* __restrict__ hist){
    const int e = blockIdx.x*256 + threadIdx.x;
    if (e < N_EDGES) atomicAdd(&hist[dst[e]], 1);
}

__global__ __launch_bounds__(1024) void scan_kernel(const int* __restrict__ hist, int* __restrict__ cursor){
    __shared__ int chunk[1024];
    const int t = threadIdx.x;
    const int base = t*25;                     // 1024*25 = 25600 >= 25000
    int local[25];
    int s = 0;
    #pragma unroll
    for (int i=0;i<25;i++){
        const int idx = base+i;
        const int v = (idx < N_NODES) ? hist[idx] : 0;
        local[i] = s; s += v;
    }
    chunk[t] = s;
    __syncthreads();
    for (int off=1; off<1024; off<<=1){
        int v = (t >= off) ? chunk[t-off] : 0;
        __syncthreads();
        chunk[t] += v;
        __syncthreads();
    }
    const int pre = (t > 0) ? chunk[t-1] : 0;
    #pragma unroll
    for (int i=0;i<25;i++){
        const int idx = base+i;
        if (idx < N_NODES) cursor[idx] = pre + local[i];
    }
}

__global__ __launch_bounds__(256) void scatter_kernel(const int* __restrict__ src, const int* __restrict__ dst,
                                                      int* __restrict__ cursor,
                                                      int* __restrict__ perm_s, int* __restrict__ src_s,
                                                      int* __restrict__ dst_s){
    const int e = blockIdx.x*256 + threadIdx.x;
    if (e < N_EDGES){
        const int d = dst[e];
        const int pos = atomicAdd(&cursor[d], 1);
        perm_s[pos] = e;
        src_s[pos]  = src[e];
        dst_s[pos]  = d;
    }
}

// ---------------------------------------------------------------- pack [3][256][256] fp32 weights into MFMA B-frag hi/lo bf16
__global__ __launch_bounds__(256) void pack_w_kernel(const float* __restrict__ w,
                                                     unsigned short* __restrict__ whi,
                                                     unsigned short* __restrict__ wlo)
{
    const int f     = blockIdx.x;          // 0..383
    const int layer = f >> 7;
    const int rem   = f & 127;
    const int ntile = rem >> 3;
    const int k8    = rem & 7;
    for (int i = threadIdx.x; i < 512; i += 256){
        const int lane = i >> 3, j = i & 7;
        const int k = k8*32 + (lane >> 4)*8 + j;
        const int n = ntile*16 + (lane & 15);
        const float v = w[(size_t)layer*HID*HID + (size_t)k*HID + n];
        const unsigned short hb = f2bf(v);
        whi[(size_t)f*512 + i] = hb;
        wlo[(size_t)f*512 + i] = f2bf(v - bf2f(hb));
    }
}

// ---------------------------------------------------------------- layer-0 edge conv (C=92, fp32), sorted edges + run merge
__global__ __launch_bounds__(128) void edge_conv92_kernel(
    const int* __restrict__ perm_s, const int* __restrict__ src_s, const int* __restrict__ dst_s,
    const float* __restrict__ ea,
    const float* __restrict__ w1, const float* __restrict__ b1,
    const float* __restrict__ w2, const float* __restrict__ b2,
    const float* __restrict__ x, float* __restrict__ agg)
{
    constexpr int C = EMB_DIM;
    constexpr int EPB = 16;
    __shared__ float h1[EPB][C];
    const int e0  = blockIdx.x * EPB;
    const int tid = threadIdx.x;

    for (int idx = tid; idx < EPB*C; idx += 128){
        const int e = idx / C, k = idx - e*C;
        const float4 a = *(const float4*)(ea + (size_t)perm_s[e0+e]*4);
        float v = fmaf(a.x, w1[k], fmaf(a.y, w1[C+k], fmaf(a.z, w1[2*C+k], fmaf(a.w, w1[3*C+k], b1[k]))));
        h1[e][k] = softplusf(v);
    }
    __syncthreads();

    const int c = tid;
    if (c < C){
        float acc[EPB];
        #pragma unroll
        for (int e=0;e<EPB;e++) acc[e] = 0.0f;
        for (int k=0;k<C;k+=4){             // 92 = 23*4
            const float w0  = w2[(k+0)*C+c];
            const float w1v = w2[(k+1)*C+c];
            const float w2v = w2[(k+2)*C+c];
            const float w3v = w2[(k+3)*C+c];
            #pragma unroll
            for (int e=0;e<EPB;e++){
                const float4 hv = *(const float4*)&h1[e][k];
                acc[e] = fmaf(hv.x,w0,fmaf(hv.y,w1v,fmaf(hv.z,w2v,fmaf(hv.w,w3v,acc[e]))));
            }
        }
        const float bb = b2[c];
        int dprev = dst_s[e0];
        float run = 0.0f;
        #pragma unroll
        for (int e=0;e<EPB;e++){
            const int eid = e0 + e;
            const int s = src_s[eid], d = dst_s[eid];
            const float msg = (acc[e] + bb) * x[(size_t)s*C + c];
            if (d != dprev){
                atomicAdd(&agg[(size_t)dprev*C + c], run);
                run = 0.0f; dprev = d;
            }
            run += msg;
        }
        atomicAdd(&agg[(size_t)dprev*C + c], run);
    }
}

// ---------------------------------------------------------------- layers 1-3 edge conv, MFMA, 32 edges/block
// A = bf16(h1) single; B = w2 hi/lo (2 MFMA). LDS 16.9KB -> 8 blocks/CU.
__global__ __launch_bounds__(256, 8) void edge_conv256_mfma_kernel(
    const int* __restrict__ perm_s, const int* __restrict__ src_s, const int* __restrict__ dst_s,
    const float* __restrict__ ea,
    const float* __restrict__ w1, const float* __restrict__ b1,
    const unsigned short* __restrict__ whi, const unsigned short* __restrict__ wlo,
    const float* __restrict__ b2,
    const float* __restrict__ x, float* __restrict__ agg)
{
    constexpr int C = HID;
    constexpr int LDA = C + 8;                 // ushort row stride 528 B -> 2-way bank alias (free)
    constexpr int EPB = 32;
    __shared__ unsigned short aHi[EPB][LDA];   // 16.9 KB
    __shared__ float eaS[EPB][4];
    __shared__ int   srcS[EPB];
    __shared__ int   dstS[EPB];

    const int e0  = blockIdx.x * EPB;          // grid = N_EDGES/32 exactly
    const int tid = threadIdx.x;

    // stage ea[perm], src, dst cooperatively (replaces ~8k broadcast VMEM ops)
    if (tid < 128){
        const int e = tid >> 2, comp = tid & 3;
        eaS[e][comp] = ea[(size_t)perm_s[e0+e]*4 + comp];
    } else if (tid < 160){
        srcS[tid-128] = src_s[e0 + tid-128];
    } else if (tid < 192){
        dstS[tid-160] = dst_s[e0 + tid-160];
    }
    __syncthreads();

    // phase 1: h1 = softplus(ea@w1+b1) -> bf16 LDS (thread = channel)
    {
        const int k = tid;
        const float w10 = w1[k], w11 = w1[C+k], w12 = w1[2*C+k], w13 = w1[3*C+k];
        const float bk  = b1[k];
        #pragma unroll
        for (int e=0;e<EPB;e++){
            const float4 a = *(const float4*)&eaS[e][0];   // LDS broadcast
            const float v = fmaf(a.x,w10,fmaf(a.y,w11,fmaf(a.z,w12,fmaf(a.w,w13,bk))));
            aHi[e][k] = f2bf(softplusf(v));
        }
    }
    __syncthreads();

    const int lane = tid & 63, wv = tid >> 6;
    const int quad = lane >> 4, fcol = lane & 15;

    f32x4 acc[2][4];
    #pragma unroll
    for (int m=0;m<2;m++)
        #pragma unroll
        for (int t=0;t<4;t++)
            #pragma unroll
            for (int j=0;j<4;j++) acc[m][t][j] = 0.0f;

    for (int k8=0;k8<8;k8++){
        bf16x8 ah[2];
        #pragma unroll
        for (int m=0;m<2;m++)
            ah[m] = *(const bf16x8*)(&aHi[m*16 + fcol][0] + k8*32 + quad*8);
        #pragma unroll
        for (int t=0;t<4;t++){
            const int fi = (wv*4 + t)*8 + k8;
            const bf16x8 bh = *(const bf16x8*)(whi + (size_t)fi*512 + lane*8);
            const bf16x8 bl = *(const bf16x8*)(wlo + (size_t)fi*512 + lane*8);
            #pragma unroll
            for (int m=0;m<2;m++){
                acc[m][t] = __builtin_amdgcn_mfma_f32_16x16x32_bf16(ah[m], bh, acc[m][t], 0, 0, 0);
                acc[m][t] = __builtin_amdgcn_mfma_f32_16x16x32_bf16(ah[m], bl, acc[m][t], 0, 0, 0);
            }
        }
    }

    // epilogue: C/D layout col = lane&15 (n), row = quad*4 + reg (edge); run-merge sorted dsts
    float bb[4];
    #pragma unroll
    for (int t=0;t<4;t++) bb[t] = b2[(wv*4 + t)*16 + fcol];

    #pragma unroll
    for (int m=0;m<2;m++){
        const int ebase = m*16 + quad*4;
        int dprev = dstS[ebase];
        float run[4] = {0.f,0.f,0.f,0.f};
        #pragma unroll
        for (int i=0;i<4;i++){
            const int s = srcS[ebase+i], d = dstS[ebase+i];
            if (d != dprev){
                #pragma unroll
                for (int t=0;t<4;t++){
                    const int n = (wv*4 + t)*16 + fcol;
                    atomicAdd(&agg[(size_t)dprev*C + n], run[t]);
                    run[t] = 0.0f;
                }
                dprev = d;
            }
            #pragma unroll
            for (int t=0;t<4;t++){
                const int n = (wv*4 + t)*16 + fcol;
                run[t] += (acc[m][t][i] + bb[t]) * x[(size_t)s*C + n];
            }
        }
        #pragma unroll
        for (int t=0;t<4;t++){
            const int n = (wv*4 + t)*16 + fcol;
            atomicAdd(&agg[(size_t)dprev*C + n], run[t]);
        }
    }
}

// ---------------------------------------------------------------- node update MFMA (CIN=256): x = softplus(agg @ nw + nb)
// A = agg hi/lo (3 MFMA — agg magnitudes are larger, keep full precision)
__global__ __launch_bounds__(256) void node_update_mfma_kernel(
    const float* __restrict__ agg,
    const unsigned short* __restrict__ whi, const unsigned short* __restrict__ wlo,
    const float* __restrict__ b, float* __restrict__ xout)
{
    constexpr int C = HID;
    constexpr int LDA = C + 8;
    __shared__ unsigned short aHi[16][LDA];
    __shared__ unsigned short aLo[16][LDA];

    const int n0  = blockIdx.x * 16;
    const int tid = threadIdx.x;

    #pragma unroll
    for (int it=0; it<16; it++){
        const int node = n0 + it;
        const float v = (node < N_NODES) ? agg[(size_t)node*C + tid] : 0.0f;
        unsigned short hb, lb;
        split_bf(v, hb, lb);
        aHi[it][tid] = hb;
        aLo[it][tid] = lb;
    }
    __syncthreads();

    const int lane = tid & 63, wv = tid >> 6;
    const int quad = lane >> 4, fcol = lane & 15;

    f32x4 acc[4];
    #pragma unroll
    for (int t=0;t<4;t++)
        #pragma unroll
        for (int j=0;j<4;j++) acc[t][j] = 0.0f;

    const unsigned short* aHrow = &aHi[fcol][0];
    const unsigned short* aLrow = &aLo[fcol][0];

    for (int k8=0;k8<8;k8++){
        const bf16x8 ah = *(const bf16x8*)(aHrow + k8*32 + quad*8);
        const bf16x8 al = *(const bf16x8*)(aLrow + k8*32 + quad*8);
        #pragma unroll
        for (int t=0;t<4;t++){
            const int fi = (wv*4 + t)*8 + k8;
            const bf16x8 bh = *(const bf16x8*)(whi + (size_t)fi*512 + lane*8);
            const bf16x8 bl = *(const bf16x8*)(wlo + (size_t)fi*512 + lane*8);
            acc[t] = __builtin_amdgcn_mfma_f32_16x16x32_bf16(ah, bh, acc[t], 0, 0, 0);
            acc[t] = __builtin_amdgcn_mfma_f32_16x16x32_bf16(ah, bl, acc[t], 0, 0, 0);
            acc[t] = __builtin_amdgcn_mfma_f32_16x16x32_bf16(al, bh, acc[t], 0, 0, 0);
        }
    }

    #pragma unroll
    for (int i=0;i<4;i++){
        const int node = n0 + quad*4 + i;
        if (node < N_NODES){
            #pragma unroll
            for (int t=0;t<4;t++){
                const int n = (wv*4 + t)*16 + fcol;
                xout[(size_t)node*C + n] = softplusf(acc[t][i] + b[n]);
            }
        }
    }
}

// ---------------------------------------------------------------- node update fp32 (layer 0, CIN=92)
__global__ __launch_bounds__(256) void node_update92_kernel(
    const float* __restrict__ agg, const float* __restrict__ w,
    const float* __restrict__ b, float* __restrict__ xout)
{
    constexpr int CIN = EMB_DIM, NPB = 4;
    __shared__ float row[NPB][CIN];
    const int n0 = blockIdx.x * NPB;
    for (int idx = threadIdx.x; idx < NPB*CIN; idx += 256){
        const int i = idx / CIN, k = idx - i*CIN;
        row[i][k] = agg[(size_t)(n0+i)*CIN + k];
    }
    __syncthreads();
    const int c = threadIdx.x;
    float acc[NPB];
    #pragma unroll
    for (int i=0;i<NPB;i++) acc[i] = b[c];
    for (int k=0;k<CIN;k+=4){
        const float w0  = w[(k+0)*HID+c];
        const float w1v = w[(k+1)*HID+c];
        const float w2v = w[(k+2)*HID+c];
        const float w3v = w[(k+3)*HID+c];
        #pragma unroll
        for (int i=0;i<NPB;i++){
            const float4 r = *(const float4*)&row[i][k];
            acc[i] = fmaf(r.x,w0,fmaf(r.y,w1v,fmaf(r.z,w2v,fmaf(r.w,w3v,acc[i]))));
        }
    }
    #pragma unroll
    for (int i=0;i<NPB;i++)
        xout[(size_t)(n0+i)*HID + c] = softplusf(acc[i]);
}

// ---------------------------------------------------------------- mean pool, run-merged (batch is sorted)
__global__ __launch_bounds__(256) void pool_kernel(
    const float* __restrict__ x, const int* __restrict__ batch,
    float* __restrict__ sums, float* __restrict__ cnts)
{
    constexpr int NPB = 32;
    const int n0 = blockIdx.x * NPB;
    const int c  = threadIdx.x;
    int gprev = batch[n0];
    float run = 0.0f, crun = 0.0f;
    for (int i=0;i<NPB;i++){
        const int n = n0 + i;
        if (n >= N_NODES) break;
        const int g = batch[n];
        if (g != gprev){
            atomicAdd(&sums[(size_t)gprev*HID + c], run);
            if (c == 0) atomicAdd(&cnts[gprev], crun);
            run = 0.0f; crun = 0.0f; gprev = g;
        }
        run  += x[(size_t)n*HID + c];
        crun += 1.0f;
    }
    atomicAdd(&sums[(size_t)gprev*HID + c], run);
    if (c == 0) atomicAdd(&cnts[gprev], crun);
}

// ---------------------------------------------------------------- readout MLP (one block per graph)
__global__ __launch_bounds__(256) void readout_kernel(
    const float* __restrict__ sums, const float* __restrict__ cnts,
    const float* __restrict__ rw1, const float* __restrict__ rb1,
    const float* __restrict__ rw2, const float* __restrict__ rb2,
    const float* __restrict__ rw3, const float* __restrict__ rb3,
    float* __restrict__ out)
{
    __shared__ float g[HID];
    __shared__ float h[HID];
    __shared__ float h2[HID/2];
    __shared__ float red[256];
    const int gi = blockIdx.x;
    const int t  = threadIdx.x;
    const float cnt = fmaxf(cnts[gi], 1.0f);
    g[t] = sums[(size_t)gi*HID + t] / cnt;
    __syncthreads();
    float acc = rb1[t];
    for (int k=0;k<HID;k++) acc = fmaf(g[k], rw1[(size_t)k*HID + t], acc);
    h[t] = softplusf(acc);
    __syncthreads();
    if (t < HID/2){
        float a2 = rb2[t];
        for (int k=0;k<HID;k++) a2 = fmaf(h[k], rw2[(size_t)k*(HID/2) + t], a2);
        h2[t] = softplusf(a2);
    }
    __syncthreads();
    red[t] = (t < HID/2) ? h2[t]*rw3[t] : 0.0f;
    __syncthreads();
    for (int s2=128; s2>0; s2>>=1){
        if (t < s2) red[t] += red[t+s2];
        __syncthreads();
    }
    if (t == 0) out[gi] = red[0] + rb3[0];
}

// ---------------------------------------------------------------- launcher
extern "C" void kernel_launch(void* const* d_in, const int* in_sizes, int n_in,
                              void* d_out, int out_size, void* d_ws, size_t ws_size,
                              hipStream_t stream)
{
    const int*   x_atoms = (const int*)d_in[0];
    const int*   eidx    = (const int*)d_in[1];
    const int*   src     = eidx;               // edge_index[0]
    const int*   dst     = eidx + N_EDGES;     // edge_index[1]
    const float* ea      = (const float*)d_in[2];
    const int*   batch   = (const int*)d_in[3];
    const float* emb     = (const float*)d_in[4];
    const float* ew1_0   = (const float*)d_in[5];
    const float* eb1_0   = (const float*)d_in[6];
    const float* ew2_0   = (const float*)d_in[7];
    const float* eb2_0   = (const float*)d_in[8];
    const float* nw_0    = (const float*)d_in[9];
    const float* nb_0    = (const float*)d_in[10];
    const float* ew1     = (const float*)d_in[11];
    const float* eb1     = (const float*)d_in[12];
    const float* ew2     = (const float*)d_in[13];
    const float* eb2     = (const float*)d_in[14];
    const float* nw      = (const float*)d_in[15];
    const float* nb      = (const float*)d_in[16];
    const float* rw1     = (const float*)d_in[17];
    const float* rb1     = (const float*)d_in[18];
    const float* rw2     = (const float*)d_in[19];
    const float* rb2     = (const float*)d_in[20];
    const float* rw3     = (const float*)d_in[21];
    const float* rb3     = (const float*)d_in[22];
    float* out = (float*)d_out;

    float* x    = (float*)d_ws;
    float* agg  = x   + (size_t)N_NODES*HID;
    float* sums = agg + (size_t)N_NODES*HID;
    float* cnts = sums + (size_t)N_GRAPHS*HID;
    unsigned short* whi  = (unsigned short*)(cnts + N_GRAPHS);
    unsigned short* wlo  = whi  + (size_t)3*128*512;
    unsigned short* nwhi = wlo  + (size_t)3*128*512;
    unsigned short* nwlo = nwhi + (size_t)3*128*512;
    int* hist   = (int*)(nwlo + (size_t)3*128*512);
    int* cursor = hist   + N_NODES;
    int* perm_s = cursor + N_NODES;
    int* src_s  = perm_s + N_EDGES;
    int* dst_s  = src_s  + N_EDGES;

    // ---- counting sort of edges by dst (once per launch) ----
    hipMemsetAsync(hist, 0, N_NODES*sizeof(int), stream);
    hipLaunchKernelGGL(hist_kernel, dim3((N_EDGES+255)/256), dim3(256), 0, stream, dst, hist);
    hipLaunchKernelGGL(scan_kernel, dim3(1), dim3(1024), 0, stream, hist, cursor);
    hipLaunchKernelGGL(scatter_kernel, dim3((N_EDGES+255)/256), dim3(256), 0, stream,
                       src, dst, cursor, perm_s, src_s, dst_s);

    // ---- pack weights for MFMA ----
    hipLaunchKernelGGL(pack_w_kernel, dim3(384), dim3(256), 0, stream, ew2, whi, wlo);
    hipLaunchKernelGGL(pack_w_kernel, dim3(384), dim3(256), 0, stream, nw, nwhi, nwlo);

    // ---- layer 0 (C = 92) ----
    hipLaunchKernelGGL(gather_emb_kernel, dim3(N_NODES), dim3(128), 0, stream, x_atoms, emb, x);
    hipMemsetAsync(agg, 0, (size_t)N_NODES*EMB_DIM*sizeof(float), stream);
    hipLaunchKernelGGL(edge_conv92_kernel, dim3(N_EDGES/16), dim3(128), 0, stream,
                       perm_s, src_s, dst_s, ea, ew1_0, eb1_0, ew2_0, eb2_0, x, agg);
    hipLaunchKernelGGL(node_update92_kernel, dim3(N_NODES/4), dim3(256), 0, stream,
                       agg, nw_0, nb_0, x);

    // ---- layers 1..3 (C = 256), MFMA ----
    for (int i=0;i<3;i++){
        hipMemsetAsync(agg, 0, (size_t)N_NODES*HID*sizeof(float), stream);
        hipLaunchKernelGGL(edge_conv256_mfma_kernel, dim3(N_EDGES/32), dim3(256), 0, stream,
                           perm_s, src_s, dst_s, ea,
                           ew1 + (size_t)i*4*HID, eb1 + (size_t)i*HID,
                           whi + (size_t)i*128*512, wlo + (size_t)i*128*512,
                           eb2 + (size_t)i*HID,
                           x, agg);
        hipLaunchKernelGGL(node_update_mfma_kernel, dim3((N_NODES+15)/16), dim3(256), 0, stream,
                           agg, nwhi + (size_t)i*128*512, nwlo + (size_t)i*128*512,
                           nb + (size_t)i*HID, x);
    }

    // ---- pool + readout ----
    hipMemsetAsync(sums, 0, ((size_t)N_GRAPHS*HID + N_GRAPHS)*sizeof(float), stream);
    hipLaunchKernelGGL(pool_kernel, dim3((N_NODES+31)/32), dim3(256), 0, stream, x, batch, sums, cnts);
    hipLaunchKernelGGL(readout_kernel, dim3(N_GRAPHS), dim3(256), 0, stream,
                       sums, cnts, rw1, rb1, rw2, rb2, rw3, rb3, out);
}